// Round 11
// baseline (8871.989 us; speedup 1.0000x reference)
//
#include <hip/hip_runtime.h>

#define BB 16
#define SS 256
#define NVOCAB 32000
#define NEMB 300

// ---- recurrence geometry ----
#define CHUNK 6            // h-indices per block (multiple of 3: chunk-aligned publish)
#define NT 384             // threads per rec block (48 k-slices x 8 row-groups)
#define NSTR 384           // hx chunk count (allocation)

typedef float f4_t __attribute__((ext_vector_type(4)));
typedef unsigned int u4_t __attribute__((ext_vector_type(4)));
typedef short bf16x8 __attribute__((ext_vector_type(8)));
typedef float f32x4 __attribute__((ext_vector_type(4)));
typedef unsigned short ushort_t;

// unaligned-safe float4 global load (rows of W are only 4B-aligned when H=1150)
__device__ __forceinline__ f4_t load_f4u(const float* p) {
    f4_t v;
    __builtin_memcpy(&v, p, sizeof(f4_t));
    return v;
}

// LLC-coherent publish: 16B store (value+tag atomic at LLC), NO drain — the
// next staging bundle's vmcnt(0) orders it; store flies concurrently.
__device__ __forceinline__ void llc_store_u4(u4_t* p, u4_t v) {
    asm volatile("global_store_dwordx4 %0, %1, off sc0 sc1" :: "v"(p), "v"(v) : "memory");
}

// 16 coherent dwordx4 loads (one base + imm offsets 0..3840) issued and WAITED
// inside one asm block. No in-flight dest reg crosses compiler-visible code.
__device__ __forceinline__ void llc_load16o_wait(
        u4_t& a0, u4_t& a1, u4_t& a2, u4_t& a3,
        u4_t& a4, u4_t& a5, u4_t& a6, u4_t& a7,
        u4_t& a8, u4_t& a9, u4_t& a10, u4_t& a11,
        u4_t& a12, u4_t& a13, u4_t& a14, u4_t& a15,
        const u4_t* p) {
    asm volatile(
        "global_load_dwordx4 %0, %16, off sc0 sc1\n\t"
        "global_load_dwordx4 %1, %16, off offset:256 sc0 sc1\n\t"
        "global_load_dwordx4 %2, %16, off offset:512 sc0 sc1\n\t"
        "global_load_dwordx4 %3, %16, off offset:768 sc0 sc1\n\t"
        "global_load_dwordx4 %4, %16, off offset:1024 sc0 sc1\n\t"
        "global_load_dwordx4 %5, %16, off offset:1280 sc0 sc1\n\t"
        "global_load_dwordx4 %6, %16, off offset:1536 sc0 sc1\n\t"
        "global_load_dwordx4 %7, %16, off offset:1792 sc0 sc1\n\t"
        "global_load_dwordx4 %8, %16, off offset:2048 sc0 sc1\n\t"
        "global_load_dwordx4 %9, %16, off offset:2304 sc0 sc1\n\t"
        "global_load_dwordx4 %10, %16, off offset:2560 sc0 sc1\n\t"
        "global_load_dwordx4 %11, %16, off offset:2816 sc0 sc1\n\t"
        "global_load_dwordx4 %12, %16, off offset:3072 sc0 sc1\n\t"
        "global_load_dwordx4 %13, %16, off offset:3328 sc0 sc1\n\t"
        "global_load_dwordx4 %14, %16, off offset:3584 sc0 sc1\n\t"
        "global_load_dwordx4 %15, %16, off offset:3840 sc0 sc1\n\t"
        "s_waitcnt vmcnt(0)"
        : "=&v"(a0), "=&v"(a1), "=&v"(a2), "=&v"(a3),
          "=&v"(a4), "=&v"(a5), "=&v"(a6), "=&v"(a7),
          "=&v"(a8), "=&v"(a9), "=&v"(a10), "=&v"(a11),
          "=&v"(a12), "=&v"(a13), "=&v"(a14), "=&v"(a15)
        : "v"(p)
        : "memory");
}

// 8 coherent dwordx4 loads (base + imm offsets 0..1792) issued + waited.
__device__ __forceinline__ void llc_load8o_wait(
        u4_t& a0, u4_t& a1, u4_t& a2, u4_t& a3,
        u4_t& a4, u4_t& a5, u4_t& a6, u4_t& a7,
        const u4_t* p) {
    asm volatile(
        "global_load_dwordx4 %0, %8, off sc0 sc1\n\t"
        "global_load_dwordx4 %1, %8, off offset:256 sc0 sc1\n\t"
        "global_load_dwordx4 %2, %8, off offset:512 sc0 sc1\n\t"
        "global_load_dwordx4 %3, %8, off offset:768 sc0 sc1\n\t"
        "global_load_dwordx4 %4, %8, off offset:1024 sc0 sc1\n\t"
        "global_load_dwordx4 %5, %8, off offset:1280 sc0 sc1\n\t"
        "global_load_dwordx4 %6, %8, off offset:1536 sc0 sc1\n\t"
        "global_load_dwordx4 %7, %8, off offset:1792 sc0 sc1\n\t"
        "s_waitcnt vmcnt(0)"
        : "=&v"(a0), "=&v"(a1), "=&v"(a2), "=&v"(a3),
          "=&v"(a4), "=&v"(a5), "=&v"(a6), "=&v"(a7)
        : "v"(p)
        : "memory");
}

// ============================ embedding ============================
__global__ void embed_kernel(const int* __restrict__ ids,
                             const float* __restrict__ emb,
                             float* __restrict__ x0) {
    int bs = blockIdx.x;
    int id = ids[bs];
    const float* row = emb + (size_t)id * NEMB;
    float* out = x0 + (size_t)bs * NEMB;
    const float scale = 17.320508075688772f;   // sqrt(300)
    for (int e = threadIdx.x; e < NEMB; e += blockDim.x)
        out[e] = row[e] * scale;
}

// ============================ fp32 -> bf16 hi/lo split (RN), padded ============================
__global__ void conv_split(const float* __restrict__ src,
                           ushort_t* __restrict__ hi, ushort_t* __restrict__ lo,
                           int N, int K, int KP, int total) {
    for (int i = blockIdx.x * blockDim.x + threadIdx.x; i < total;
         i += gridDim.x * blockDim.x) {
        int r = i / KP, k = i - r * KP;
        float v = (r < N && k < K) ? src[(size_t)r * K + k] : 0.f;
        unsigned u = __float_as_uint(v);
        unsigned hb = (u + 0x7FFFu + ((u >> 16) & 1u)) >> 16;
        float hf = __uint_as_float(hb << 16);
        float rem = v - hf;
        unsigned u2 = __float_as_uint(rem);
        unsigned lb = (u2 + 0x7FFFu + ((u2 >> 16) & 1u)) >> 16;
        hi[i] = (ushort_t)hb;
        lo[i] = (ushort_t)lb;
    }
}

// ============================ bf16-split MFMA GEMM ============================
// C = A[M=4096,KP] * W[NP,KP]^T (+bias), via Ah*Wh + Ah*Wl + Al*Wh.
// 128x128 tile, 4 waves (2x2), each wave 64x64 = 4x4 16x16x32 fragments.
// permuted=1 -> C[(s*BB+b)*N + n] with m = b*256+s; col-guard n < N.
__global__ __launch_bounds__(256) void gemm_mfma(
        const ushort_t* __restrict__ Ah, const ushort_t* __restrict__ Al,
        const ushort_t* __restrict__ Wh, const ushort_t* __restrict__ Wl,
        float* __restrict__ C, int N, int KP,
        const float* __restrict__ bias_i, const float* __restrict__ bias_h,
        int permuted) {
    constexpr int LD = 40;             // LDS row stride (bf16): 32 + 8 pad
    __shared__ ushort_t sA[2][128 * LD];
    __shared__ ushort_t sW[2][128 * LD];
    const int t    = threadIdx.x;
    const int lane = t & 63;
    const int wave = t >> 6;
    const int wm   = wave >> 1, wn = wave & 1;
    const int n0   = blockIdx.x * 128;
    const int m0   = blockIdx.y * 128;

    f32x4 acc[4][4];
    #pragma unroll
    for (int i = 0; i < 4; i++)
        #pragma unroll
        for (int j = 0; j < 4; j++)
            acc[i][j] = (f32x4){0.f, 0.f, 0.f, 0.f};

    const int nkt = KP >> 5;
    for (int kt = 0; kt < nkt; kt++) {
        __syncthreads();
        #pragma unroll
        for (int c = 0; c < 2; c++) {
            int id = t + c * 256;          // 0..511
            int r = id >> 2, kq = id & 3;
            int so = r * LD + kq * 8;
            size_t goA = (size_t)(m0 + r) * KP + kt * 32 + kq * 8;
            size_t goW = (size_t)(n0 + r) * KP + kt * 32 + kq * 8;
            *reinterpret_cast<u4_t*>(&sA[0][so]) = *reinterpret_cast<const u4_t*>(Ah + goA);
            *reinterpret_cast<u4_t*>(&sA[1][so]) = *reinterpret_cast<const u4_t*>(Al + goA);
            *reinterpret_cast<u4_t*>(&sW[0][so]) = *reinterpret_cast<const u4_t*>(Wh + goW);
            *reinterpret_cast<u4_t*>(&sW[1][so]) = *reinterpret_cast<const u4_t*>(Wl + goW);
        }
        __syncthreads();

        bf16x8 ah[4], al[4], wh[4], wl[4];
        #pragma unroll
        for (int i = 0; i < 4; i++) {
            int ro = (wm * 64 + i * 16 + (lane & 15)) * LD + (lane >> 4) * 8;
            int co = (wn * 64 + i * 16 + (lane & 15)) * LD + (lane >> 4) * 8;
            ah[i] = *reinterpret_cast<const bf16x8*>(&sA[0][ro]);
            al[i] = *reinterpret_cast<const bf16x8*>(&sA[1][ro]);
            wh[i] = *reinterpret_cast<const bf16x8*>(&sW[0][co]);
            wl[i] = *reinterpret_cast<const bf16x8*>(&sW[1][co]);
        }
        #pragma unroll
        for (int i = 0; i < 4; i++)
            #pragma unroll
            for (int j = 0; j < 4; j++) {
                acc[i][j] = __builtin_amdgcn_mfma_f32_16x16x32_bf16(ah[i], wh[j], acc[i][j], 0, 0, 0);
                acc[i][j] = __builtin_amdgcn_mfma_f32_16x16x32_bf16(ah[i], wl[j], acc[i][j], 0, 0, 0);
                acc[i][j] = __builtin_amdgcn_mfma_f32_16x16x32_bf16(al[i], wh[j], acc[i][j], 0, 0, 0);
            }
    }

    // epilogue: C/D layout col=lane&15, row=(lane>>4)*4+reg
    #pragma unroll
    for (int i = 0; i < 4; i++) {
        int row = m0 + wm * 64 + i * 16 + ((lane >> 4) << 2);
        #pragma unroll
        for (int j = 0; j < 4; j++) {
            int col = n0 + wn * 64 + j * 16 + (lane & 15);
            if (col < N) {
                float bv = bias_i ? (bias_i[col] + bias_h[col]) : 0.f;
                #pragma unroll
                for (int r2 = 0; r2 < 4; r2++) {
                    int m = row + r2;
                    float v = acc[i][j][r2] + bv;
                    size_t idx;
                    if (permuted) {
                        int b_ = m >> 8;      // S = 256
                        int s_ = m & 255;
                        idx = ((size_t)s_ * BB + b_) * (size_t)N + col;
                    } else {
                        idx = (size_t)m * (size_t)N + col;
                    }
                    C[idx] = v;
                }
            }
        }
    }
}

// ============================ persistent LSTM recurrence (v7) ============================
// r10 compute/reduce/gates structure; staging upgraded: hx tiled
// [2][colgrp16][row16][col16] so thread t's 16 row-chunks sit at one base +
// imm offsets 0..3840 -> ALL 16 issued in ONE bundle (1 LLC RT). Retry is
// per-8-group (both stale -> 16, one stale -> that 8): latency ~max not sum,
// retry quantum <= r7's proven 8. Publish store is NOT drained (next bundle's
// vmcnt(0) orders it) so it flies concurrently with staging.
template<int SW, int NCHR>
__global__ __launch_bounds__(NT, 1) void lstm_rec(
        const float* __restrict__ Whh,   // [4H][H]
        const float* __restrict__ xg,    // [S][B][4H]
        float* __restrict__ xout,        // [B][S][H]
        u4_t* __restrict__ hx,           // [2][NSTR/16][16][16] chunks
        int H, unsigned TB) {
    constexpr int KP   = 48 * SW;        // padded K (>= H)
    constexpr int LDH  = KP + 4;         // ht row stride
    constexpr int NSUB = SW / 8;         // 8-col sub-phases per slice
    constexpr int PRS  = 17;             // pbuf row stride (conflict-free)
    constexpr int PSS  = 24 * PRS + 4;   // pbuf slot stride = 412
    extern __shared__ __align__(16) float lds[];
    float* ht   = lds;                   // [16][LDH]
    float* pbuf = ht + 16 * LDH;         // [24][PSS]
    float* gbuf = pbuf + 24 * PSS;       // [NT]   (row*16+b)
    float* cbuf = gbuf + NT;             // [96]
    float* hlx  = cbuf + 96;             // [96]

    const int t    = threadIdx.x;
    const int lane = t & 63;
    const int wv   = t >> 6;             // wave 0..5
    const int ks   = t >> 3;             // 0..47
    const int rg   = t & 7;              // 0..7
    const int h0   = blockIdx.x * CHUNK;
    const int G4   = 4 * H;

    // W row pointers (invalid rows clamped to row 0; results discarded later)
    const float* wr[3];
    #pragma unroll
    for (int j = 0; j < 3; j++) {
        int r = 3 * rg + j, g = r / CHUNK, l = r - g * CHUNK;
        int grow = ((h0 + l) < H) ? (g * H + h0 + l) : 0;
        wr[j] = Whh + (size_t)grow * (size_t)H;
    }

    // zero ht (covers pad cols / never-staged region) and c state
    for (int i = t; i < 16 * LDH; i += NT) ht[i] = 0.f;
    if (t < 96) cbuf[t] = 0.f;
    __syncthreads();

    // reducer/output role: (r_row = t>>4, r_b = t&15)
    const int r_row = t >> 4, r_b = t & 15;
    const int r_g = r_row / CHUNK, r_l = r_row - r_g * CHUNK;
    const int r_h = ((h0 + r_l) < H) ? (h0 + r_l) : h0;
    const float* xgp = xg + (size_t)r_b * G4 + (size_t)r_g * H + r_h;

    const int pairidx = (lane >> 4) & 3;
    const int prow3   = 3 * (lane & 7);

    // staging base chunk: thread t owns chunk-id t (h cols 3t..3t+2), rows 0..15
    const int stg_base = (t >> 4) * 256 + (t & 15);

    #pragma unroll 1
    for (int s = 0; s < SS; s++) {
        const u4_t* hcb = hx + (size_t)(s & 1) * (16 * NSTR);        // consume
        u4_t*       hpb = hx + (size_t)((s + 1) & 1) * (16 * NSTR);  // produce
        const unsigned tgt = TB + (unsigned)s;
        float xgv = xgp[(size_t)s * (size_t)(16 * G4)];

        // ---- stage h tile: one 16-load bundle; per-8-group retry ----
        if (s > 0 && t < NCHR) {
            const u4_t* p = hcb + stg_base;
            u4_t u0, u1, u2, u3, u4v, u5v, u6v, u7v;
            u4_t u8v, u9v, u10v, u11v, u12v, u13v, u14v, u15v;
            llc_load16o_wait(u0, u1, u2, u3, u4v, u5v, u6v, u7v,
                             u8v, u9v, u10v, u11v, u12v, u13v, u14v, u15v, p);
            for (;;) {
                int okA = (u0.w  >= tgt) & (u1.w  >= tgt) & (u2.w  >= tgt) & (u3.w  >= tgt)
                        & (u4v.w >= tgt) & (u5v.w >= tgt) & (u6v.w >= tgt) & (u7v.w >= tgt);
                int okB = (u8v.w >= tgt) & (u9v.w >= tgt) & (u10v.w >= tgt) & (u11v.w >= tgt)
                        & (u12v.w >= tgt) & (u13v.w >= tgt) & (u14v.w >= tgt) & (u15v.w >= tgt);
                if (okA & okB) break;
                if (!okA & !okB)
                    llc_load16o_wait(u0, u1, u2, u3, u4v, u5v, u6v, u7v,
                                     u8v, u9v, u10v, u11v, u12v, u13v, u14v, u15v, p);
                else if (!okA)
                    llc_load8o_wait(u0, u1, u2, u3, u4v, u5v, u6v, u7v, p);
                else
                    llc_load8o_wait(u8v, u9v, u10v, u11v, u12v, u13v, u14v, u15v, p + 128);
            }
            float* d;
            d = ht +  0 * LDH + 3 * t; d[0] = __uint_as_float(u0.x);  d[1] = __uint_as_float(u0.y);  d[2] = __uint_as_float(u0.z);
            d = ht +  1 * LDH + 3 * t; d[0] = __uint_as_float(u1.x);  d[1] = __uint_as_float(u1.y);  d[2] = __uint_as_float(u1.z);
            d = ht +  2 * LDH + 3 * t; d[0] = __uint_as_float(u2.x);  d[1] = __uint_as_float(u2.y);  d[2] = __uint_as_float(u2.z);
            d = ht +  3 * LDH + 3 * t; d[0] = __uint_as_float(u3.x);  d[1] = __uint_as_float(u3.y);  d[2] = __uint_as_float(u3.z);
            d = ht +  4 * LDH + 3 * t; d[0] = __uint_as_float(u4v.x); d[1] = __uint_as_float(u4v.y); d[2] = __uint_as_float(u4v.z);
            d = ht +  5 * LDH + 3 * t; d[0] = __uint_as_float(u5v.x); d[1] = __uint_as_float(u5v.y); d[2] = __uint_as_float(u5v.z);
            d = ht +  6 * LDH + 3 * t; d[0] = __uint_as_float(u6v.x); d[1] = __uint_as_float(u6v.y); d[2] = __uint_as_float(u6v.z);
            d = ht +  7 * LDH + 3 * t; d[0] = __uint_as_float(u7v.x); d[1] = __uint_as_float(u7v.y); d[2] = __uint_as_float(u7v.z);
            d = ht +  8 * LDH + 3 * t; d[0] = __uint_as_float(u8v.x); d[1] = __uint_as_float(u8v.y); d[2] = __uint_as_float(u8v.z);
            d = ht +  9 * LDH + 3 * t; d[0] = __uint_as_float(u9v.x); d[1] = __uint_as_float(u9v.y); d[2] = __uint_as_float(u9v.z);
            d = ht + 10 * LDH + 3 * t; d[0] = __uint_as_float(u10v.x); d[1] = __uint_as_float(u10v.y); d[2] = __uint_as_float(u10v.z);
            d = ht + 11 * LDH + 3 * t; d[0] = __uint_as_float(u11v.x); d[1] = __uint_as_float(u11v.y); d[2] = __uint_as_float(u11v.z);
            d = ht + 12 * LDH + 3 * t; d[0] = __uint_as_float(u12v.x); d[1] = __uint_as_float(u12v.y); d[2] = __uint_as_float(u12v.z);
            d = ht + 13 * LDH + 3 * t; d[0] = __uint_as_float(u13v.x); d[1] = __uint_as_float(u13v.y); d[2] = __uint_as_float(u13v.z);
            d = ht + 14 * LDH + 3 * t; d[0] = __uint_as_float(u14v.x); d[1] = __uint_as_float(u14v.y); d[2] = __uint_as_float(u14v.z);
            d = ht + 15 * LDH + 3 * t; d[0] = __uint_as_float(u15v.x); d[1] = __uint_as_float(u15v.y); d[2] = __uint_as_float(u15v.z);
        }
        __syncthreads();

        // ---- per-thread partial dots (W streamed from L2, h from LDS) ----
        float a[3][16];
        #pragma unroll
        for (int j = 0; j < 3; j++)
            #pragma unroll
            for (int b = 0; b < 16; b++) a[j][b] = 0.f;

        if (s > 0) {
            #pragma unroll
            for (int sub = 0; sub < NSUB; sub++) {
                const int kk = ks * SW + sub * 8;
                const int k0 = (kk < H) ? kk : 0;          // clamp; h=0 in pad
                const int k1 = (kk + 4 < H) ? (kk + 4) : 0;
                const f4_t w00 = load_f4u(wr[0] + k0), w01 = load_f4u(wr[0] + k1);
                const f4_t w10 = load_f4u(wr[1] + k0), w11 = load_f4u(wr[1] + k1);
                const f4_t w20 = load_f4u(wr[2] + k0), w21 = load_f4u(wr[2] + k1);
                const float* hb = ht + kk;
                #pragma unroll
                for (int b = 0; b < 16; b++) {
                    const f4_t h0v = *reinterpret_cast<const f4_t*>(hb + b * LDH);
                    const f4_t h1v = *reinterpret_cast<const f4_t*>(hb + b * LDH + 4);
                    float acc;
                    acc = a[0][b];
                    acc = fmaf(w00.x, h0v.x, acc); acc = fmaf(w00.y, h0v.y, acc);
                    acc = fmaf(w00.z, h0v.z, acc); acc = fmaf(w00.w, h0v.w, acc);
                    acc = fmaf(w01.x, h1v.x, acc); acc = fmaf(w01.y, h1v.y, acc);
                    acc = fmaf(w01.z, h1v.z, acc); acc = fmaf(w01.w, h1v.w, acc);
                    a[0][b] = acc;
                    acc = a[1][b];
                    acc = fmaf(w10.x, h0v.x, acc); acc = fmaf(w10.y, h0v.y, acc);
                    acc = fmaf(w10.z, h0v.z, acc); acc = fmaf(w10.w, h0v.w, acc);
                    acc = fmaf(w11.x, h1v.x, acc); acc = fmaf(w11.y, h1v.y, acc);
                    acc = fmaf(w11.z, h1v.z, acc); acc = fmaf(w11.w, h1v.w, acc);
                    a[1][b] = acc;
                    acc = a[2][b];
                    acc = fmaf(w20.x, h0v.x, acc); acc = fmaf(w20.y, h0v.y, acc);
                    acc = fmaf(w20.z, h0v.z, acc); acc = fmaf(w20.w, h0v.w, acc);
                    acc = fmaf(w21.x, h1v.x, acc); acc = fmaf(w21.y, h1v.y, acc);
                    acc = fmaf(w21.z, h1v.z, acc); acc = fmaf(w21.w, h1v.w, acc);
                    a[2][b] = acc;
                }
            }
        }

        // ---- reduce k-slices: 1 shfl level (ks pairs) -> 24-slot pbuf ----
        #pragma unroll
        for (int j = 0; j < 3; j++)
            #pragma unroll
            for (int b = 0; b < 16; b++) {
                float v = a[j][b] + __shfl_xor(a[j][b], 8);
                if ((lane & 8) == 0)
                    pbuf[(wv * 4 + pairidx) * PSS + (prow3 + j) * PRS + b] = v;
            }
        __syncthreads();

        // ---- final reduce + bias from xg ----
        {
            float dot = xgv;
            #pragma unroll
            for (int q = 0; q < 24; q++)
                dot += pbuf[q * PSS + r_row * PRS + r_b];
            gbuf[t] = dot;
        }
        __syncthreads();

        // ---- gates ----
        if (t < 96) {
            int l = t >> 4, b = t & 15;
            float gi = gbuf[(0 * CHUNK + l) * 16 + b];
            float gf = gbuf[(1 * CHUNK + l) * 16 + b];
            float gg = gbuf[(2 * CHUNK + l) * 16 + b];
            float go = gbuf[(3 * CHUNK + l) * 16 + b];
            float iv = 1.f / (1.f + expf(-gi));
            float fv = 1.f / (1.f + expf(-gf));
            float gv = tanhf(gg);
            float ov = 1.f / (1.f + expf(-go));
            float c  = fv * cbuf[t] + iv * gv;
            cbuf[t]  = c;
            float hv = ov * tanhf(c);
            hv = ((h0 + l) < H) ? hv : 0.f;
            hlx[b * CHUNK + l] = hv;
            if ((h0 + l) < H)
                xout[(size_t)b * ((size_t)SS * H) + (size_t)s * H + (h0 + l)] = hv;
        }
        __syncthreads();

        // ---- pack + publish this block's 2 chunks per batch row (no drain) ----
        if (t < 32) {
            int bq = t >> 1, cj = t & 1;
            u4_t pk;
            pk.x = __float_as_uint(hlx[bq * CHUNK + 3 * cj + 0]);
            pk.y = __float_as_uint(hlx[bq * CHUNK + 3 * cj + 1]);
            pk.z = __float_as_uint(hlx[bq * CHUNK + 3 * cj + 2]);
            pk.w = tgt + 1u;
            int c = (h0 / 3) + cj;
            llc_store_u4(hpb + ((c >> 4) * 256 + bq * 16 + (c & 15)), pk);
        }
    }
}

// ============================ launch ============================
extern "C" void kernel_launch(void* const* d_in, const int* in_sizes, int n_in,
                              void* d_out, int out_size, void* d_ws, size_t ws_size,
                              hipStream_t stream) {
    const int*   ids  = (const int*)d_in[0];
    const float* emb  = (const float*)d_in[1];
    const float* Wih0 = (const float*)d_in[2];
    const float* Whh0 = (const float*)d_in[3];
    const float* bih0 = (const float*)d_in[4];
    const float* bhh0 = (const float*)d_in[5];
    const float* Wih1 = (const float*)d_in[6];
    const float* Whh1 = (const float*)d_in[7];
    const float* bih1 = (const float*)d_in[8];
    const float* bhh1 = (const float*)d_in[9];
    const float* Wih2 = (const float*)d_in[10];
    const float* Whh2 = (const float*)d_in[11];
    const float* bih2 = (const float*)d_in[12];
    const float* bhh2 = (const float*)d_in[13];
    float* out = (float*)d_out;

    // workspace layout (floats)
    float* ws = (float*)d_ws;
    float* xA = ws;                        // 1,228,800  (x0, later x3)
    float* xB = xA + 1228800;              // 4,710,400  (x1, later x2; then final Ah/Al)
    float* xg = xB + 4710400;              // 18,841,600 (gates; then final Wh/Wl)
    u4_t*  hx = (u4_t*)(xg + 18841600);    // [2][24][16][16] chunks = 196,608 B
    (void)in_sizes; (void)n_in; (void)out_size; (void)ws_size;

    // d_out as scratch for input-projection splits (fully rewritten at the end)
    ushort_t* sc  = (ushort_t*)d_out;
    ushort_t* tAh = sc;                               // [4096][1152] max
    ushort_t* tAl = tAh + (size_t)4096 * 1152;
    ushort_t* W0h = tAl + (size_t)4096 * 1152;        // [4608][320]
    ushort_t* W0l = W0h + (size_t)4608 * 320;
    ushort_t* W1h = W0l + (size_t)4608 * 320;         // [4608][1152]
    ushort_t* W1l = W1h + (size_t)4608 * 1152;
    ushort_t* W2h = W1l + (size_t)4608 * 1152;        // [1280][1152]
    ushort_t* W2l = W2h + (size_t)1280 * 1152;

    // final-projection splits (workspace regions dead by then)
    ushort_t* fAh = (ushort_t*)xB;                    // [4096][320]
    ushort_t* fAl = fAh + (size_t)4096 * 320;
    ushort_t* fWh = (ushort_t*)xg;                    // [32000][320]
    ushort_t* fWl = fWh + (size_t)32000 * 320;

    // zero tags once per launch (graph-captured, replay-safe)
    hipMemsetAsync(hx, 0, (size_t)2 * 16 * NSTR * 16, stream);

    // LDS bytes
    const size_t lds01 = (size_t)(16 * 1156 + 24 * 412 + NT + 96 + 96) * 4;  // 115,840
    const size_t lds2  = (size_t)(16 * 388  + 24 * 412 + NT + 96 + 96) * 4;  //  66,688

    // ---- static weight splits ----
    conv_split<<<dim3(720), dim3(256), 0, stream>>>(Wih0, W0h, W0l, 4600, 300, 320, 4608 * 320);
    conv_split<<<dim3(2048), dim3(256), 0, stream>>>(Wih1, W1h, W1l, 4600, 1150, 1152, 4608 * 1152);
    conv_split<<<dim3(720), dim3(256), 0, stream>>>(Wih2, W2h, W2l, 1200, 1150, 1152, 1280 * 1152);

    // ---- embedding ----
    embed_kernel<<<dim3(BB * SS), dim3(256), 0, stream>>>(ids, emb, xA);

    // ---- layer 0 ----
    conv_split<<<dim3(640), dim3(256), 0, stream>>>(xA, tAh, tAl, 4096, 300, 320, 4096 * 320);
    gemm_mfma<<<dim3(36, 32), dim3(256), 0, stream>>>(tAh, tAl, W0h, W0l, xg,
                                                      4600, 320, bih0, bhh0, 1);
    lstm_rec<24, 384><<<dim3(192), dim3(NT), lds01, stream>>>(Whh0, xg, xB, hx, 1150, 0u);

    // ---- layer 1 ----
    conv_split<<<dim3(2048), dim3(256), 0, stream>>>(xB, tAh, tAl, 4096, 1150, 1152, 4096 * 1152);
    gemm_mfma<<<dim3(36, 32), dim3(256), 0, stream>>>(tAh, tAl, W1h, W1l, xg,
                                                      4600, 1152, bih1, bhh1, 1);
    lstm_rec<24, 384><<<dim3(192), dim3(NT), lds01, stream>>>(Whh1, xg, xB, hx, 1150, 256u);

    // ---- layer 2 ----
    conv_split<<<dim3(2048), dim3(256), 0, stream>>>(xB, tAh, tAl, 4096, 1150, 1152, 4096 * 1152);
    gemm_mfma<<<dim3(10, 32), dim3(256), 0, stream>>>(tAh, tAl, W2h, W2l, xg,
                                                      1200, 1152, bih2, bhh2, 1);
    lstm_rec<8, 100><<<dim3(50), dim3(NT), lds2, stream>>>(Whh2, xg, xA, hx, 300, 512u);

    // ---- final projection splits (xB/xg dead; d_out scratch no longer needed) ----
    conv_split<<<dim3(640), dim3(256), 0, stream>>>(xA, fAh, fAl, 4096, 300, 320, 4096 * 320);
    conv_split<<<dim3(2048), dim3(256), 0, stream>>>(emb, fWh, fWl, 32000, 300, 320, 32000 * 320);

    // ---- tied output projection via bf16-split MFMA ----
    gemm_mfma<<<dim3(250, 32), dim3(256), 0, stream>>>(fAh, fAl, fWh, fWl, out,
                                                       NVOCAB, 320, nullptr, nullptr, 0);
}

// Round 13
// 8518.642 us; speedup vs baseline: 1.0415x; 1.0415x over previous
//
#include <hip/hip_runtime.h>

#define BB 16
#define SS 256
#define NVOCAB 32000
#define NEMB 300

// ---- recurrence geometry ----
#define CHUNK 6            // h-indices per block (multiple of 3: chunk-aligned publish)
#define NT 384             // threads per rec block (48 k-slices x 8 row-groups)
#define NSTR 384           // hx chunk stride per batch row

typedef float f4_t __attribute__((ext_vector_type(4)));
typedef unsigned int u4_t __attribute__((ext_vector_type(4)));
typedef short bf16x8 __attribute__((ext_vector_type(8)));
typedef float f32x4 __attribute__((ext_vector_type(4)));
typedef unsigned short ushort_t;

// unaligned-safe float4 global load (rows of W are only 4B-aligned when H=1150)
__device__ __forceinline__ f4_t load_f4u(const float* p) {
    f4_t v;
    __builtin_memcpy(&v, p, sizeof(f4_t));
    return v;
}

// LLC-coherent publish: 16B store (value+tag atomic at LLC) + drain inside asm
__device__ __forceinline__ void llc_store_u4_drain(u4_t* p, u4_t v) {
    asm volatile("global_store_dwordx4 %0, %1, off sc0 sc1\n\t"
                 "s_waitcnt vmcnt(0)" :: "v"(p), "v"(v) : "memory");
}

// Bundled coherent loads: 8 x dwordx4 issued and WAITED inside one asm block.
// No in-flight destination register ever crosses compiler-visible code.
__device__ __forceinline__ void llc_load8_wait(
        u4_t& u0, u4_t& u1, u4_t& u2, u4_t& u3,
        u4_t& u4v, u4_t& u5v, u4_t& u6v, u4_t& u7v,
        const u4_t* p0, const u4_t* p1, const u4_t* p2, const u4_t* p3,
        const u4_t* p4, const u4_t* p5, const u4_t* p6, const u4_t* p7) {
    asm volatile(
        "global_load_dwordx4 %0, %8, off sc0 sc1\n\t"
        "global_load_dwordx4 %1, %9, off sc0 sc1\n\t"
        "global_load_dwordx4 %2, %10, off sc0 sc1\n\t"
        "global_load_dwordx4 %3, %11, off sc0 sc1\n\t"
        "global_load_dwordx4 %4, %12, off sc0 sc1\n\t"
        "global_load_dwordx4 %5, %13, off sc0 sc1\n\t"
        "global_load_dwordx4 %6, %14, off sc0 sc1\n\t"
        "global_load_dwordx4 %7, %15, off sc0 sc1\n\t"
        "s_waitcnt vmcnt(0)"
        : "=&v"(u0), "=&v"(u1), "=&v"(u2), "=&v"(u3),
          "=&v"(u4v), "=&v"(u5v), "=&v"(u6v), "=&v"(u7v)
        : "v"(p0), "v"(p1), "v"(p2), "v"(p3),
          "v"(p4), "v"(p5), "v"(p6), "v"(p7)
        : "memory");
}

// ============================ embedding ============================
__global__ void embed_kernel(const int* __restrict__ ids,
                             const float* __restrict__ emb,
                             float* __restrict__ x0) {
    int bs = blockIdx.x;
    int id = ids[bs];
    const float* row = emb + (size_t)id * NEMB;
    float* out = x0 + (size_t)bs * NEMB;
    const float scale = 17.320508075688772f;   // sqrt(300)
    for (int e = threadIdx.x; e < NEMB; e += blockDim.x)
        out[e] = row[e] * scale;
}

// ============================ fp32 -> bf16 hi/lo split (RN), padded ============================
__global__ void conv_split(const float* __restrict__ src,
                           ushort_t* __restrict__ hi, ushort_t* __restrict__ lo,
                           int N, int K, int KP, int total) {
    for (int i = blockIdx.x * blockDim.x + threadIdx.x; i < total;
         i += gridDim.x * blockDim.x) {
        int r = i / KP, k = i - r * KP;
        float v = (r < N && k < K) ? src[(size_t)r * K + k] : 0.f;
        unsigned u = __float_as_uint(v);
        unsigned hb = (u + 0x7FFFu + ((u >> 16) & 1u)) >> 16;
        float hf = __uint_as_float(hb << 16);
        float rem = v - hf;
        unsigned u2 = __float_as_uint(rem);
        unsigned lb = (u2 + 0x7FFFu + ((u2 >> 16) & 1u)) >> 16;
        hi[i] = (ushort_t)hb;
        lo[i] = (ushort_t)lb;
    }
}

// ============================ bf16-split MFMA GEMM ============================
// C = A[M=4096,KP] * W[NP,KP]^T (+bias), via Ah*Wh + Ah*Wl + Al*Wh.
// 128x128 tile, 4 waves (2x2), each wave 64x64 = 4x4 16x16x32 fragments.
// permuted=1 -> C[(s*BB+b)*N + n] with m = b*256+s; col-guard n < N.
__global__ __launch_bounds__(256) void gemm_mfma(
        const ushort_t* __restrict__ Ah, const ushort_t* __restrict__ Al,
        const ushort_t* __restrict__ Wh, const ushort_t* __restrict__ Wl,
        float* __restrict__ C, int N, int KP,
        const float* __restrict__ bias_i, const float* __restrict__ bias_h,
        int permuted) {
    constexpr int LD = 40;             // LDS row stride (bf16): 32 + 8 pad
    __shared__ ushort_t sA[2][128 * LD];
    __shared__ ushort_t sW[2][128 * LD];
    const int t    = threadIdx.x;
    const int lane = t & 63;
    const int wave = t >> 6;
    const int wm   = wave >> 1, wn = wave & 1;
    const int n0   = blockIdx.x * 128;
    const int m0   = blockIdx.y * 128;

    f32x4 acc[4][4];
    #pragma unroll
    for (int i = 0; i < 4; i++)
        #pragma unroll
        for (int j = 0; j < 4; j++)
            acc[i][j] = (f32x4){0.f, 0.f, 0.f, 0.f};

    const int nkt = KP >> 5;
    for (int kt = 0; kt < nkt; kt++) {
        __syncthreads();
        #pragma unroll
        for (int c = 0; c < 2; c++) {
            int id = t + c * 256;          // 0..511
            int r = id >> 2, kq = id & 3;
            int so = r * LD + kq * 8;
            size_t goA = (size_t)(m0 + r) * KP + kt * 32 + kq * 8;
            size_t goW = (size_t)(n0 + r) * KP + kt * 32 + kq * 8;
            *reinterpret_cast<u4_t*>(&sA[0][so]) = *reinterpret_cast<const u4_t*>(Ah + goA);
            *reinterpret_cast<u4_t*>(&sA[1][so]) = *reinterpret_cast<const u4_t*>(Al + goA);
            *reinterpret_cast<u4_t*>(&sW[0][so]) = *reinterpret_cast<const u4_t*>(Wh + goW);
            *reinterpret_cast<u4_t*>(&sW[1][so]) = *reinterpret_cast<const u4_t*>(Wl + goW);
        }
        __syncthreads();

        bf16x8 ah[4], al[4], wh[4], wl[4];
        #pragma unroll
        for (int i = 0; i < 4; i++) {
            int ro = (wm * 64 + i * 16 + (lane & 15)) * LD + (lane >> 4) * 8;
            int co = (wn * 64 + i * 16 + (lane & 15)) * LD + (lane >> 4) * 8;
            ah[i] = *reinterpret_cast<const bf16x8*>(&sA[0][ro]);
            al[i] = *reinterpret_cast<const bf16x8*>(&sA[1][ro]);
            wh[i] = *reinterpret_cast<const bf16x8*>(&sW[0][co]);
            wl[i] = *reinterpret_cast<const bf16x8*>(&sW[1][co]);
        }
        #pragma unroll
        for (int i = 0; i < 4; i++)
            #pragma unroll
            for (int j = 0; j < 4; j++) {
                acc[i][j] = __builtin_amdgcn_mfma_f32_16x16x32_bf16(ah[i], wh[j], acc[i][j], 0, 0, 0);
                acc[i][j] = __builtin_amdgcn_mfma_f32_16x16x32_bf16(ah[i], wl[j], acc[i][j], 0, 0, 0);
                acc[i][j] = __builtin_amdgcn_mfma_f32_16x16x32_bf16(al[i], wh[j], acc[i][j], 0, 0, 0);
            }
    }

    // epilogue: C/D layout col=lane&15, row=(lane>>4)*4+reg
    #pragma unroll
    for (int i = 0; i < 4; i++) {
        int row = m0 + wm * 64 + i * 16 + ((lane >> 4) << 2);
        #pragma unroll
        for (int j = 0; j < 4; j++) {
            int col = n0 + wn * 64 + j * 16 + (lane & 15);
            if (col < N) {
                float bv = bias_i ? (bias_i[col] + bias_h[col]) : 0.f;
                #pragma unroll
                for (int r2 = 0; r2 < 4; r2++) {
                    int m = row + r2;
                    float v = acc[i][j][r2] + bv;
                    size_t idx;
                    if (permuted) {
                        int b_ = m >> 8;      // S = 256
                        int s_ = m & 255;
                        idx = ((size_t)s_ * BB + b_) * (size_t)N + col;
                    } else {
                        idx = (size_t)m * (size_t)N + col;
                    }
                    C[idx] = v;
                }
            }
        }
    }
}

// ============================ persistent LSTM recurrence (r10 + backoff A/B) ============================
// Thread (ks = t>>3, rg = t&7): partial dots for 3 gate rows over its k-slice.
// W streamed from L2 into transient regs; h exchanged as 16B {h0,h1,h2,tag}
// chunks via sc0|sc1; two 8-load bundled issue+wait stages with whole-8
// parallel retry (proven best of 6 variants). BOFF>0 adds s_sleep backoff
// after each FAILED retry to thin the LLC poll storm (L1 treatment vs L0
// control; within-run A/B).
template<int SW, int NCHR, int BOFF>
__global__ __launch_bounds__(NT, 1) void lstm_rec(
        const float* __restrict__ Whh,   // [4H][H]
        const float* __restrict__ xg,    // [S][B][4H]
        float* __restrict__ xout,        // [B][S][H]
        u4_t* __restrict__ hx,           // [2][16][NSTR] chunks
        int H, unsigned TB) {
    constexpr int KP   = 48 * SW;        // padded K (>= H)
    constexpr int LDH  = KP + 4;         // ht row stride
    constexpr int NSUB = SW / 8;         // 8-col sub-phases per slice
    constexpr int PRS  = 17;             // pbuf row stride (conflict-free)
    constexpr int PSS  = 24 * PRS + 4;   // pbuf slot stride = 412
    extern __shared__ __align__(16) float lds[];
    float* ht   = lds;                   // [16][LDH]
    float* pbuf = ht + 16 * LDH;         // [24][PSS]
    float* gbuf = pbuf + 24 * PSS;       // [NT]   (row*16+b)
    float* cbuf = gbuf + NT;             // [96]
    float* hlx  = cbuf + 96;             // [96]

    const int t    = threadIdx.x;
    const int lane = t & 63;
    const int wv   = t >> 6;             // wave 0..5
    const int ks   = t >> 3;             // 0..47
    const int rg   = t & 7;              // 0..7
    const int h0   = blockIdx.x * CHUNK;
    const int G4   = 4 * H;

    // W row pointers (invalid rows clamped to row 0; results discarded later)
    const float* wr[3];
    #pragma unroll
    for (int j = 0; j < 3; j++) {
        int r = 3 * rg + j, g = r / CHUNK, l = r - g * CHUNK;
        int grow = ((h0 + l) < H) ? (g * H + h0 + l) : 0;
        wr[j] = Whh + (size_t)grow * (size_t)H;
    }

    // zero ht (covers pad cols / never-staged region) and c state
    for (int i = t; i < 16 * LDH; i += NT) ht[i] = 0.f;
    if (t < 96) cbuf[t] = 0.f;
    __syncthreads();

    // reducer/output role: (r_row = t>>4, r_b = t&15)
    const int r_row = t >> 4, r_b = t & 15;
    const int r_g = r_row / CHUNK, r_l = r_row - r_g * CHUNK;
    const int r_h = ((h0 + r_l) < H) ? (h0 + r_l) : h0;
    const float* xgp = xg + (size_t)r_b * G4 + (size_t)r_g * H + r_h;

    const int pairidx = (lane >> 4) & 3;
    const int prow3   = 3 * (lane & 7);

    #pragma unroll 1
    for (int s = 0; s < SS; s++) {
        const u4_t* hcb = hx + (size_t)(s & 1) * (16 * NSTR);        // consume
        u4_t*       hpb = hx + (size_t)((s + 1) & 1) * (16 * NSTR);  // produce
        const unsigned tgt = TB + (unsigned)s;
        float xgv = xgp[(size_t)s * (size_t)(16 * G4)];

        // ---- stage h tile (skip at s==0: ht stays zero) ----
        if (s > 0 && t < NCHR) {
            const u4_t* cb = hcb + t;
            #pragma unroll
            for (int rh = 0; rh < 2; rh++) {
                const u4_t* q0 = cb + (rh * 8 + 0) * NSTR;
                const u4_t* q1 = cb + (rh * 8 + 1) * NSTR;
                const u4_t* q2 = cb + (rh * 8 + 2) * NSTR;
                const u4_t* q3 = cb + (rh * 8 + 3) * NSTR;
                const u4_t* q4 = cb + (rh * 8 + 4) * NSTR;
                const u4_t* q5 = cb + (rh * 8 + 5) * NSTR;
                const u4_t* q6 = cb + (rh * 8 + 6) * NSTR;
                const u4_t* q7 = cb + (rh * 8 + 7) * NSTR;
                u4_t u0, u1, u2, u3, u4v, u5v, u6v, u7v;
                for (;;) {
                    llc_load8_wait(u0, u1, u2, u3, u4v, u5v, u6v, u7v,
                                   q0, q1, q2, q3, q4, q5, q6, q7);
                    int ok = (u0.w >= tgt) & (u1.w >= tgt) & (u2.w >= tgt) & (u3.w >= tgt)
                           & (u4v.w >= tgt) & (u5v.w >= tgt) & (u6v.w >= tgt) & (u7v.w >= tgt);
                    if (ok) break;
                    if constexpr (BOFF > 0) __builtin_amdgcn_s_sleep(BOFF);
                }
                float* d;
                d = ht + (rh * 8 + 0) * LDH + 3 * t;
                d[0] = __uint_as_float(u0.x); d[1] = __uint_as_float(u0.y); d[2] = __uint_as_float(u0.z);
                d = ht + (rh * 8 + 1) * LDH + 3 * t;
                d[0] = __uint_as_float(u1.x); d[1] = __uint_as_float(u1.y); d[2] = __uint_as_float(u1.z);
                d = ht + (rh * 8 + 2) * LDH + 3 * t;
                d[0] = __uint_as_float(u2.x); d[1] = __uint_as_float(u2.y); d[2] = __uint_as_float(u2.z);
                d = ht + (rh * 8 + 3) * LDH + 3 * t;
                d[0] = __uint_as_float(u3.x); d[1] = __uint_as_float(u3.y); d[2] = __uint_as_float(u3.z);
                d = ht + (rh * 8 + 4) * LDH + 3 * t;
                d[0] = __uint_as_float(u4v.x); d[1] = __uint_as_float(u4v.y); d[2] = __uint_as_float(u4v.z);
                d = ht + (rh * 8 + 5) * LDH + 3 * t;
                d[0] = __uint_as_float(u5v.x); d[1] = __uint_as_float(u5v.y); d[2] = __uint_as_float(u5v.z);
                d = ht + (rh * 8 + 6) * LDH + 3 * t;
                d[0] = __uint_as_float(u6v.x); d[1] = __uint_as_float(u6v.y); d[2] = __uint_as_float(u6v.z);
                d = ht + (rh * 8 + 7) * LDH + 3 * t;
                d[0] = __uint_as_float(u7v.x); d[1] = __uint_as_float(u7v.y); d[2] = __uint_as_float(u7v.z);
            }
        }
        __syncthreads();

        // ---- per-thread partial dots (W streamed from L2, h from LDS) ----
        float a[3][16];
        #pragma unroll
        for (int j = 0; j < 3; j++)
            #pragma unroll
            for (int b = 0; b < 16; b++) a[j][b] = 0.f;

        if (s > 0) {
            #pragma unroll
            for (int sub = 0; sub < NSUB; sub++) {
                const int kk = ks * SW + sub * 8;
                const int k0 = (kk < H) ? kk : 0;          // clamp; h=0 in pad
                const int k1 = (kk + 4 < H) ? (kk + 4) : 0;
                const f4_t w00 = load_f4u(wr[0] + k0), w01 = load_f4u(wr[0] + k1);
                const f4_t w10 = load_f4u(wr[1] + k0), w11 = load_f4u(wr[1] + k1);
                const f4_t w20 = load_f4u(wr[2] + k0), w21 = load_f4u(wr[2] + k1);
                const float* hb = ht + kk;
                #pragma unroll
                for (int b = 0; b < 16; b++) {
                    const f4_t h0v = *reinterpret_cast<const f4_t*>(hb + b * LDH);
                    const f4_t h1v = *reinterpret_cast<const f4_t*>(hb + b * LDH + 4);
                    float acc;
                    acc = a[0][b];
                    acc = fmaf(w00.x, h0v.x, acc); acc = fmaf(w00.y, h0v.y, acc);
                    acc = fmaf(w00.z, h0v.z, acc); acc = fmaf(w00.w, h0v.w, acc);
                    acc = fmaf(w01.x, h1v.x, acc); acc = fmaf(w01.y, h1v.y, acc);
                    acc = fmaf(w01.z, h1v.z, acc); acc = fmaf(w01.w, h1v.w, acc);
                    a[0][b] = acc;
                    acc = a[1][b];
                    acc = fmaf(w10.x, h0v.x, acc); acc = fmaf(w10.y, h0v.y, acc);
                    acc = fmaf(w10.z, h0v.z, acc); acc = fmaf(w10.w, h0v.w, acc);
                    acc = fmaf(w11.x, h1v.x, acc); acc = fmaf(w11.y, h1v.y, acc);
                    acc = fmaf(w11.z, h1v.z, acc); acc = fmaf(w11.w, h1v.w, acc);
                    a[1][b] = acc;
                    acc = a[2][b];
                    acc = fmaf(w20.x, h0v.x, acc); acc = fmaf(w20.y, h0v.y, acc);
                    acc = fmaf(w20.z, h0v.z, acc); acc = fmaf(w20.w, h0v.w, acc);
                    acc = fmaf(w21.x, h1v.x, acc); acc = fmaf(w21.y, h1v.y, acc);
                    acc = fmaf(w21.z, h1v.z, acc); acc = fmaf(w21.w, h1v.w, acc);
                    a[2][b] = acc;
                }
            }
        }

        // ---- reduce k-slices: 1 shfl level (ks pairs) -> 24-slot pbuf ----
        #pragma unroll
        for (int j = 0; j < 3; j++)
            #pragma unroll
            for (int b = 0; b < 16; b++) {
                float v = a[j][b] + __shfl_xor(a[j][b], 8);
                if ((lane & 8) == 0)
                    pbuf[(wv * 4 + pairidx) * PSS + (prow3 + j) * PRS + b] = v;
            }
        __syncthreads();

        // ---- final reduce + bias from xg ----
        {
            float dot = xgv;
            #pragma unroll
            for (int q = 0; q < 24; q++)
                dot += pbuf[q * PSS + r_row * PRS + r_b];
            gbuf[t] = dot;
        }
        __syncthreads();

        // ---- gates ----
        if (t < 96) {
            int l = t >> 4, b = t & 15;
            float gi = gbuf[(0 * CHUNK + l) * 16 + b];
            float gf = gbuf[(1 * CHUNK + l) * 16 + b];
            float gg = gbuf[(2 * CHUNK + l) * 16 + b];
            float go = gbuf[(3 * CHUNK + l) * 16 + b];
            float iv = 1.f / (1.f + expf(-gi));
            float fv = 1.f / (1.f + expf(-gf));
            float gv = tanhf(gg);
            float ov = 1.f / (1.f + expf(-go));
            float c  = fv * cbuf[t] + iv * gv;
            cbuf[t]  = c;
            float hv = ov * tanhf(c);
            hv = ((h0 + l) < H) ? hv : 0.f;
            hlx[b * CHUNK + l] = hv;
            if ((h0 + l) < H)
                xout[(size_t)b * ((size_t)SS * H) + (size_t)s * H + (h0 + l)] = hv;
        }
        __syncthreads();

        // ---- pack + publish this block's 2 chunks per batch row ----
        if (t < 32) {
            int bq = t >> 1, cj = t & 1;
            u4_t pk;
            pk.x = __float_as_uint(hlx[bq * CHUNK + 3 * cj + 0]);
            pk.y = __float_as_uint(hlx[bq * CHUNK + 3 * cj + 1]);
            pk.z = __float_as_uint(hlx[bq * CHUNK + 3 * cj + 2]);
            pk.w = tgt + 1u;
            llc_store_u4_drain(hpb + bq * NSTR + (h0 / 3 + cj), pk);
        }
    }
}

// ============================ launch ============================
extern "C" void kernel_launch(void* const* d_in, const int* in_sizes, int n_in,
                              void* d_out, int out_size, void* d_ws, size_t ws_size,
                              hipStream_t stream) {
    const int*   ids  = (const int*)d_in[0];
    const float* emb  = (const float*)d_in[1];
    const float* Wih0 = (const float*)d_in[2];
    const float* Whh0 = (const float*)d_in[3];
    const float* bih0 = (const float*)d_in[4];
    const float* bhh0 = (const float*)d_in[5];
    const float* Wih1 = (const float*)d_in[6];
    const float* Whh1 = (const float*)d_in[7];
    const float* bih1 = (const float*)d_in[8];
    const float* bhh1 = (const float*)d_in[9];
    const float* Wih2 = (const float*)d_in[10];
    const float* Whh2 = (const float*)d_in[11];
    const float* bih2 = (const float*)d_in[12];
    const float* bhh2 = (const float*)d_in[13];
    float* out = (float*)d_out;

    // workspace layout (floats)
    float* ws = (float*)d_ws;
    float* xA = ws;                        // 1,228,800  (x0, later x3)
    float* xB = xA + 1228800;              // 4,710,400  (x1, later x2; then final Ah/Al)
    float* xg = xB + 4710400;              // 18,841,600 (gates; then final Wh/Wl)
    u4_t*  hx = (u4_t*)(xg + 18841600);    // [2][16][NSTR] chunks = 196,608 B
    (void)in_sizes; (void)n_in; (void)out_size; (void)ws_size;

    // d_out as scratch for input-projection splits (fully rewritten at the end)
    ushort_t* sc  = (ushort_t*)d_out;
    ushort_t* tAh = sc;                               // [4096][1152] max
    ushort_t* tAl = tAh + (size_t)4096 * 1152;
    ushort_t* W0h = tAl + (size_t)4096 * 1152;        // [4608][320]
    ushort_t* W0l = W0h + (size_t)4608 * 320;
    ushort_t* W1h = W0l + (size_t)4608 * 320;         // [4608][1152]
    ushort_t* W1l = W1h + (size_t)4608 * 1152;
    ushort_t* W2h = W1l + (size_t)4608 * 1152;        // [1280][1152]
    ushort_t* W2l = W2h + (size_t)1280 * 1152;

    // final-projection splits (workspace regions dead by then)
    ushort_t* fAh = (ushort_t*)xB;                    // [4096][320]
    ushort_t* fAl = fAh + (size_t)4096 * 320;
    ushort_t* fWh = (ushort_t*)xg;                    // [32000][320]
    ushort_t* fWl = fWh + (size_t)32000 * 320;

    // zero tags once per launch (graph-captured, replay-safe)
    hipMemsetAsync(hx, 0, (size_t)2 * 16 * NSTR * 16, stream);

    // LDS bytes
    const size_t lds01 = (size_t)(16 * 1156 + 24 * 412 + NT + 96 + 96) * 4;  // 115,840
    const size_t lds2  = (size_t)(16 * 388  + 24 * 412 + NT + 96 + 96) * 4;  //  66,688

    // ---- static weight splits ----
    conv_split<<<dim3(720), dim3(256), 0, stream>>>(Wih0, W0h, W0l, 4600, 300, 320, 4608 * 320);
    conv_split<<<dim3(2048), dim3(256), 0, stream>>>(Wih1, W1h, W1l, 4600, 1150, 1152, 4608 * 1152);
    conv_split<<<dim3(720), dim3(256), 0, stream>>>(Wih2, W2h, W2l, 1200, 1150, 1152, 1280 * 1152);

    // ---- embedding ----
    embed_kernel<<<dim3(BB * SS), dim3(256), 0, stream>>>(ids, emb, xA);

    // ---- layer 0 (control: no backoff) ----
    conv_split<<<dim3(640), dim3(256), 0, stream>>>(xA, tAh, tAl, 4096, 300, 320, 4096 * 320);
    gemm_mfma<<<dim3(36, 32), dim3(256), 0, stream>>>(tAh, tAl, W0h, W0l, xg,
                                                      4600, 320, bih0, bhh0, 1);
    lstm_rec<24, 384, 0><<<dim3(192), dim3(NT), lds01, stream>>>(Whh0, xg, xB, hx, 1150, 0u);

    // ---- layer 1 (treatment: s_sleep(16) backoff on failed retries) ----
    conv_split<<<dim3(2048), dim3(256), 0, stream>>>(xB, tAh, tAl, 4096, 1150, 1152, 4096 * 1152);
    gemm_mfma<<<dim3(36, 32), dim3(256), 0, stream>>>(tAh, tAl, W1h, W1l, xg,
                                                      4600, 1152, bih1, bhh1, 1);
    lstm_rec<24, 384, 16><<<dim3(192), dim3(NT), lds01, stream>>>(Whh1, xg, xB, hx, 1150, 256u);

    // ---- layer 2 (backoff) ----
    conv_split<<<dim3(2048), dim3(256), 0, stream>>>(xB, tAh, tAl, 4096, 1150, 1152, 4096 * 1152);
    gemm_mfma<<<dim3(10, 32), dim3(256), 0, stream>>>(tAh, tAl, W2h, W2l, xg,
                                                      1200, 1152, bih2, bhh2, 1);
    lstm_rec<8, 100, 16><<<dim3(50), dim3(NT), lds2, stream>>>(Whh2, xg, xA, hx, 300, 512u);

    // ---- final projection splits (xB/xg dead; d_out scratch no longer needed) ----
    conv_split<<<dim3(640), dim3(256), 0, stream>>>(xA, fAh, fAl, 4096, 300, 320, 4096 * 320);
    conv_split<<<dim3(2048), dim3(256), 0, stream>>>(emb, fWh, fWl, 32000, 300, 320, 32000 * 320);

    // ---- tied output projection via bf16-split MFMA ----
    gemm_mfma<<<dim3(250, 32), dim3(256), 0, stream>>>(fAh, fAl, fWh, fWl, out,
                                                       NVOCAB, 320, nullptr, nullptr, 0);
}

// Round 14
// 8508.833 us; speedup vs baseline: 1.0427x; 1.0012x over previous
//
#include <hip/hip_runtime.h>

#define BB 16
#define SS 256
#define NVOCAB 32000
#define NEMB 300

// ---- recurrence geometry ----
#define CHUNK 6            // h-indices per block (multiple of 3: chunk-aligned publish)
#define NT 384             // threads per rec block (48 k-slices x 8 row-groups)
#define NSTR 384           // hx chunk stride per batch row

typedef float f4_t __attribute__((ext_vector_type(4)));
typedef unsigned int u4_t __attribute__((ext_vector_type(4)));
typedef short bf16x8 __attribute__((ext_vector_type(8)));
typedef float f32x4 __attribute__((ext_vector_type(4)));
typedef unsigned short ushort_t;

// unaligned-safe float4 global load
__device__ __forceinline__ f4_t load_f4u(const float* p) {
    f4_t v;
    __builtin_memcpy(&v, p, sizeof(f4_t));
    return v;
}

// LLC-coherent publish: 16B store (value+tag atomic at LLC) + drain inside asm
__device__ __forceinline__ void llc_store_u4_drain(u4_t* p, u4_t v) {
    asm volatile("global_store_dwordx4 %0, %1, off sc0 sc1\n\t"
                 "s_waitcnt vmcnt(0)" :: "v"(p), "v"(v) : "memory");
}

// Bundled coherent loads: 8 x dwordx4 issued and WAITED inside one asm block.
// No in-flight destination register ever crosses compiler-visible code.
__device__ __forceinline__ void llc_load8_wait(
        u4_t& u0, u4_t& u1, u4_t& u2, u4_t& u3,
        u4_t& u4v, u4_t& u5v, u4_t& u6v, u4_t& u7v,
        const u4_t* p0, const u4_t* p1, const u4_t* p2, const u4_t* p3,
        const u4_t* p4, const u4_t* p5, const u4_t* p6, const u4_t* p7) {
    asm volatile(
        "global_load_dwordx4 %0, %8, off sc0 sc1\n\t"
        "global_load_dwordx4 %1, %9, off sc0 sc1\n\t"
        "global_load_dwordx4 %2, %10, off sc0 sc1\n\t"
        "global_load_dwordx4 %3, %11, off sc0 sc1\n\t"
        "global_load_dwordx4 %4, %12, off sc0 sc1\n\t"
        "global_load_dwordx4 %5, %13, off sc0 sc1\n\t"
        "global_load_dwordx4 %6, %14, off sc0 sc1\n\t"
        "global_load_dwordx4 %7, %15, off sc0 sc1\n\t"
        "s_waitcnt vmcnt(0)"
        : "=&v"(u0), "=&v"(u1), "=&v"(u2), "=&v"(u3),
          "=&v"(u4v), "=&v"(u5v), "=&v"(u6v), "=&v"(u7v)
        : "v"(p0), "v"(p1), "v"(p2), "v"(p3),
          "v"(p4), "v"(p5), "v"(p6), "v"(p7)
        : "memory");
}

// ============================ embedding ============================
__global__ void embed_kernel(const int* __restrict__ ids,
                             const float* __restrict__ emb,
                             float* __restrict__ x0) {
    int bs = blockIdx.x;
    int id = ids[bs];
    const float* row = emb + (size_t)id * NEMB;
    float* out = x0 + (size_t)bs * NEMB;
    const float scale = 17.320508075688772f;   // sqrt(300)
    for (int e = threadIdx.x; e < NEMB; e += blockDim.x)
        out[e] = row[e] * scale;
}

// ============================ fp32 -> bf16 hi/lo split (RN), padded ============================
__global__ void conv_split(const float* __restrict__ src,
                           ushort_t* __restrict__ hi, ushort_t* __restrict__ lo,
                           int N, int K, int KP, int total) {
    for (int i = blockIdx.x * blockDim.x + threadIdx.x; i < total;
         i += gridDim.x * blockDim.x) {
        int r = i / KP, k = i - r * KP;
        float v = (r < N && k < K) ? src[(size_t)r * K + k] : 0.f;
        unsigned u = __float_as_uint(v);
        unsigned hb = (u + 0x7FFFu + ((u >> 16) & 1u)) >> 16;
        float hf = __uint_as_float(hb << 16);
        float rem = v - hf;
        unsigned u2 = __float_as_uint(rem);
        unsigned lb = (u2 + 0x7FFFu + ((u2 >> 16) & 1u)) >> 16;
        hi[i] = (ushort_t)hb;
        lo[i] = (ushort_t)lb;
    }
}

// ============================ bf16-split MFMA GEMM ============================
__global__ __launch_bounds__(256) void gemm_mfma(
        const ushort_t* __restrict__ Ah, const ushort_t* __restrict__ Al,
        const ushort_t* __restrict__ Wh, const ushort_t* __restrict__ Wl,
        float* __restrict__ C, int N, int KP,
        const float* __restrict__ bias_i, const float* __restrict__ bias_h,
        int permuted) {
    constexpr int LD = 40;             // LDS row stride (bf16): 32 + 8 pad
    __shared__ ushort_t sA[2][128 * LD];
    __shared__ ushort_t sW[2][128 * LD];
    const int t    = threadIdx.x;
    const int lane = t & 63;
    const int wave = t >> 6;
    const int wm   = wave >> 1, wn = wave & 1;
    const int n0   = blockIdx.x * 128;
    const int m0   = blockIdx.y * 128;

    f32x4 acc[4][4];
    #pragma unroll
    for (int i = 0; i < 4; i++)
        #pragma unroll
        for (int j = 0; j < 4; j++)
            acc[i][j] = (f32x4){0.f, 0.f, 0.f, 0.f};

    const int nkt = KP >> 5;
    for (int kt = 0; kt < nkt; kt++) {
        __syncthreads();
        #pragma unroll
        for (int c = 0; c < 2; c++) {
            int id = t + c * 256;          // 0..511
            int r = id >> 2, kq = id & 3;
            int so = r * LD + kq * 8;
            size_t goA = (size_t)(m0 + r) * KP + kt * 32 + kq * 8;
            size_t goW = (size_t)(n0 + r) * KP + kt * 32 + kq * 8;
            *reinterpret_cast<u4_t*>(&sA[0][so]) = *reinterpret_cast<const u4_t*>(Ah + goA);
            *reinterpret_cast<u4_t*>(&sA[1][so]) = *reinterpret_cast<const u4_t*>(Al + goA);
            *reinterpret_cast<u4_t*>(&sW[0][so]) = *reinterpret_cast<const u4_t*>(Wh + goW);
            *reinterpret_cast<u4_t*>(&sW[1][so]) = *reinterpret_cast<const u4_t*>(Wl + goW);
        }
        __syncthreads();

        bf16x8 ah[4], al[4], wh[4], wl[4];
        #pragma unroll
        for (int i = 0; i < 4; i++) {
            int ro = (wm * 64 + i * 16 + (lane & 15)) * LD + (lane >> 4) * 8;
            int co = (wn * 64 + i * 16 + (lane & 15)) * LD + (lane >> 4) * 8;
            ah[i] = *reinterpret_cast<const bf16x8*>(&sA[0][ro]);
            al[i] = *reinterpret_cast<const bf16x8*>(&sA[1][ro]);
            wh[i] = *reinterpret_cast<const bf16x8*>(&sW[0][co]);
            wl[i] = *reinterpret_cast<const bf16x8*>(&sW[1][co]);
        }
        #pragma unroll
        for (int i = 0; i < 4; i++)
            #pragma unroll
            for (int j = 0; j < 4; j++) {
                acc[i][j] = __builtin_amdgcn_mfma_f32_16x16x32_bf16(ah[i], wh[j], acc[i][j], 0, 0, 0);
                acc[i][j] = __builtin_amdgcn_mfma_f32_16x16x32_bf16(ah[i], wl[j], acc[i][j], 0, 0, 0);
                acc[i][j] = __builtin_amdgcn_mfma_f32_16x16x32_bf16(al[i], wh[j], acc[i][j], 0, 0, 0);
            }
    }

    // epilogue: C/D layout col=lane&15, row=(lane>>4)*4+reg
    #pragma unroll
    for (int i = 0; i < 4; i++) {
        int row = m0 + wm * 64 + i * 16 + ((lane >> 4) << 2);
        #pragma unroll
        for (int j = 0; j < 4; j++) {
            int col = n0 + wn * 64 + j * 16 + (lane & 15);
            if (col < N) {
                float bv = bias_i ? (bias_i[col] + bias_h[col]) : 0.f;
                #pragma unroll
                for (int r2 = 0; r2 < 4; r2++) {
                    int m = row + r2;
                    float v = acc[i][j][r2] + bv;
                    size_t idx;
                    if (permuted) {
                        int b_ = m >> 8;      // S = 256
                        int s_ = m & 255;
                        idx = ((size_t)s_ * BB + b_) * (size_t)N + col;
                    } else {
                        idx = (size_t)m * (size_t)N + col;
                    }
                    C[idx] = v;
                }
            }
        }
    }
}

// ============================ W-in-LDS persistent LSTM recurrence (L0 treatment) ============================
// W slice (24 rows x 1152) lives in LDS in lane-consecutive swizzled layout
// wp[(j*3+sub)*2+q][t][4] -> conflict-free ds_read_b128, ZERO W memory traffic
// per step (tests the W-stream-stall theory). h tile processed in two batch
// halves of 8 (ht[8][1156] fits beside W). Staging = proven two 8-bundles,
// interleaved stageA/computeA/stageB/computeB. Full-wave shfl reduce (3 lvls),
// 6-slot pbuf. Exchange protocol identical to r10.
__global__ __launch_bounds__(NT, 1) void lstm_recW(
        const float* __restrict__ Whh,   // [4H][H]
        const float* __restrict__ xg,    // [S][B][4H]
        float* __restrict__ xout,        // [B][S][H]
        u4_t* __restrict__ hx,           // [2][16][NSTR] chunks
        int H, unsigned TB) {
    constexpr int LDH = 1156;            // ht row stride
    constexpr int PRS = 17;              // pbuf row stride
    constexpr int PSS = 24 * PRS + 4;    // 412
    extern __shared__ __align__(16) float lds[];
    float* wp   = lds;                   // [18][384][4] = 27648 floats (110,592 B)
    float* ht   = wp + 27648;            // [8][1156] = 9248 (36,992 B)
    float* pbuf = ht + 9248;             // [6][412] = 2472 (9,888 B)
    float* gbuf = pbuf + 6 * PSS;        // [384]
    float* cbuf = gbuf + NT;             // [96]
    float* hlx  = cbuf + 96;             // [96]

    const int t    = threadIdx.x;
    const int lane = t & 63;
    const int wv   = t >> 6;             // wave 0..5
    const int ks   = t >> 3;             // 0..47
    const int rg   = t & 7;              // 0..7
    const int h0   = blockIdx.x * CHUNK;
    const int G4   = 4 * H;

    f4_t* wp4 = reinterpret_cast<f4_t*>(wp);

    // ---- one-time: swizzle this block's W slice into LDS ----
    #pragma unroll
    for (int j = 0; j < 3; j++) {
        int r = 3 * rg + j, g = r / CHUNK, l = r - g * CHUNK;
        bool okr = (h0 + l) < H;
        const float* src = Whh + (size_t)(okr ? (g * H + h0 + l) : 0) * (size_t)H;
        #pragma unroll
        for (int sub = 0; sub < 3; sub++)
            #pragma unroll
            for (int q = 0; q < 2; q++) {
                int k = ks * 24 + sub * 8 + q * 4;
                f4_t v; v.x = 0.f; v.y = 0.f; v.z = 0.f; v.w = 0.f;
                if (okr) {
                    if (k + 0 < H) v.x = src[k + 0];
                    if (k + 1 < H) v.y = src[k + 1];
                    if (k + 2 < H) v.z = src[k + 2];
                    if (k + 3 < H) v.w = src[k + 3];
                }
                wp4[((j * 3 + sub) * 2 + q) * NT + t] = v;
            }
    }
    for (int i = t; i < 8 * LDH; i += NT) ht[i] = 0.f;
    if (t < 96) cbuf[t] = 0.f;
    __syncthreads();

    // reducer/output role: (r_row = t>>4, r_b = t&15)
    const int r_row = t >> 4, r_b = t & 15;
    const int r_g = r_row / CHUNK, r_l = r_row - r_g * CHUNK;
    const int r_h = ((h0 + r_l) < H) ? (h0 + r_l) : h0;
    const float* xgp = xg + (size_t)r_b * G4 + (size_t)r_g * H + r_h;
    const int prow3 = 3 * rg;

    #pragma unroll 1
    for (int s = 0; s < SS; s++) {
        const u4_t* hcb = hx + (size_t)(s & 1) * (16 * NSTR);        // consume
        u4_t*       hpb = hx + (size_t)((s + 1) & 1) * (16 * NSTR);  // produce
        const unsigned tgt = TB + (unsigned)s;
        float xgv = xgp[(size_t)s * (size_t)(16 * G4)];
        const u4_t* cb = hcb + t;

        // ---- stage half A (batch rows 0..7) ----
        if (s > 0) {
            u4_t u0, u1, u2, u3, u4v, u5v, u6v, u7v;
            for (;;) {
                llc_load8_wait(u0, u1, u2, u3, u4v, u5v, u6v, u7v,
                               cb + 0 * NSTR, cb + 1 * NSTR, cb + 2 * NSTR, cb + 3 * NSTR,
                               cb + 4 * NSTR, cb + 5 * NSTR, cb + 6 * NSTR, cb + 7 * NSTR);
                int ok = (u0.w >= tgt) & (u1.w >= tgt) & (u2.w >= tgt) & (u3.w >= tgt)
                       & (u4v.w >= tgt) & (u5v.w >= tgt) & (u6v.w >= tgt) & (u7v.w >= tgt);
                if (ok) break;
            }
            float* d;
            d = ht + 0 * LDH + 3 * t; d[0] = __uint_as_float(u0.x);  d[1] = __uint_as_float(u0.y);  d[2] = __uint_as_float(u0.z);
            d = ht + 1 * LDH + 3 * t; d[0] = __uint_as_float(u1.x);  d[1] = __uint_as_float(u1.y);  d[2] = __uint_as_float(u1.z);
            d = ht + 2 * LDH + 3 * t; d[0] = __uint_as_float(u2.x);  d[1] = __uint_as_float(u2.y);  d[2] = __uint_as_float(u2.z);
            d = ht + 3 * LDH + 3 * t; d[0] = __uint_as_float(u3.x);  d[1] = __uint_as_float(u3.y);  d[2] = __uint_as_float(u3.z);
            d = ht + 4 * LDH + 3 * t; d[0] = __uint_as_float(u4v.x); d[1] = __uint_as_float(u4v.y); d[2] = __uint_as_float(u4v.z);
            d = ht + 5 * LDH + 3 * t; d[0] = __uint_as_float(u5v.x); d[1] = __uint_as_float(u5v.y); d[2] = __uint_as_float(u5v.z);
            d = ht + 6 * LDH + 3 * t; d[0] = __uint_as_float(u6v.x); d[1] = __uint_as_float(u6v.y); d[2] = __uint_as_float(u6v.z);
            d = ht + 7 * LDH + 3 * t; d[0] = __uint_as_float(u7v.x); d[1] = __uint_as_float(u7v.y); d[2] = __uint_as_float(u7v.z);
        }
        __syncthreads();

        // ---- compute half A (b = 0..7), W from LDS (conflict-free) ----
        {
            float a[3][8];
            #pragma unroll
            for (int j = 0; j < 3; j++)
                #pragma unroll
                for (int b = 0; b < 8; b++) a[j][b] = 0.f;
            if (s > 0) {
                #pragma unroll
                for (int sub = 0; sub < 3; sub++) {
                    const f4_t w00 = wp4[((0 * 3 + sub) * 2 + 0) * NT + t];
                    const f4_t w01 = wp4[((0 * 3 + sub) * 2 + 1) * NT + t];
                    const f4_t w10 = wp4[((1 * 3 + sub) * 2 + 0) * NT + t];
                    const f4_t w11 = wp4[((1 * 3 + sub) * 2 + 1) * NT + t];
                    const f4_t w20 = wp4[((2 * 3 + sub) * 2 + 0) * NT + t];
                    const f4_t w21 = wp4[((2 * 3 + sub) * 2 + 1) * NT + t];
                    const float* hb = ht + ks * 24 + sub * 8;
                    #pragma unroll
                    for (int b = 0; b < 8; b++) {
                        const f4_t h0v = *reinterpret_cast<const f4_t*>(hb + b * LDH);
                        const f4_t h1v = *reinterpret_cast<const f4_t*>(hb + b * LDH + 4);
                        float acc;
                        acc = a[0][b];
                        acc = fmaf(w00.x, h0v.x, acc); acc = fmaf(w00.y, h0v.y, acc);
                        acc = fmaf(w00.z, h0v.z, acc); acc = fmaf(w00.w, h0v.w, acc);
                        acc = fmaf(w01.x, h1v.x, acc); acc = fmaf(w01.y, h1v.y, acc);
                        acc = fmaf(w01.z, h1v.z, acc); acc = fmaf(w01.w, h1v.w, acc);
                        a[0][b] = acc;
                        acc = a[1][b];
                        acc = fmaf(w10.x, h0v.x, acc); acc = fmaf(w10.y, h0v.y, acc);
                        acc = fmaf(w10.z, h0v.z, acc); acc = fmaf(w10.w, h0v.w, acc);
                        acc = fmaf(w11.x, h1v.x, acc); acc = fmaf(w11.y, h1v.y, acc);
                        acc = fmaf(w11.z, h1v.z, acc); acc = fmaf(w11.w, h1v.w, acc);
                        a[1][b] = acc;
                        acc = a[2][b];
                        acc = fmaf(w20.x, h0v.x, acc); acc = fmaf(w20.y, h0v.y, acc);
                        acc = fmaf(w20.z, h0v.z, acc); acc = fmaf(w20.w, h0v.w, acc);
                        acc = fmaf(w21.x, h1v.x, acc); acc = fmaf(w21.y, h1v.y, acc);
                        acc = fmaf(w21.z, h1v.z, acc); acc = fmaf(w21.w, h1v.w, acc);
                        a[2][b] = acc;
                    }
                }
            }
            // full-wave reduce over the 8 ks in this wave -> lane<8 writes pbuf
            #pragma unroll
            for (int j = 0; j < 3; j++)
                #pragma unroll
                for (int b = 0; b < 8; b++) {
                    float v = a[j][b];
                    v += __shfl_xor(v, 8);
                    v += __shfl_xor(v, 16);
                    v += __shfl_xor(v, 32);
                    if (lane < 8)
                        pbuf[wv * PSS + (prow3 + j) * PRS + b] = v;
                }
        }
        __syncthreads();   // computeA readers done with ht; pbuf A written

        // ---- stage half B (batch rows 8..15) into same ht tile ----
        if (s > 0) {
            u4_t u0, u1, u2, u3, u4v, u5v, u6v, u7v;
            for (;;) {
                llc_load8_wait(u0, u1, u2, u3, u4v, u5v, u6v, u7v,
                               cb + 8 * NSTR, cb + 9 * NSTR, cb + 10 * NSTR, cb + 11 * NSTR,
                               cb + 12 * NSTR, cb + 13 * NSTR, cb + 14 * NSTR, cb + 15 * NSTR);
                int ok = (u0.w >= tgt) & (u1.w >= tgt) & (u2.w >= tgt) & (u3.w >= tgt)
                       & (u4v.w >= tgt) & (u5v.w >= tgt) & (u6v.w >= tgt) & (u7v.w >= tgt);
                if (ok) break;
            }
            float* d;
            d = ht + 0 * LDH + 3 * t; d[0] = __uint_as_float(u0.x);  d[1] = __uint_as_float(u0.y);  d[2] = __uint_as_float(u0.z);
            d = ht + 1 * LDH + 3 * t; d[0] = __uint_as_float(u1.x);  d[1] = __uint_as_float(u1.y);  d[2] = __uint_as_float(u1.z);
            d = ht + 2 * LDH + 3 * t; d[0] = __uint_as_float(u2.x);  d[1] = __uint_as_float(u2.y);  d[2] = __uint_as_float(u2.z);
            d = ht + 3 * LDH + 3 * t; d[0] = __uint_as_float(u3.x);  d[1] = __uint_as_float(u3.y);  d[2] = __uint_as_float(u3.z);
            d = ht + 4 * LDH + 3 * t; d[0] = __uint_as_float(u4v.x); d[1] = __uint_as_float(u4v.y); d[2] = __uint_as_float(u4v.z);
            d = ht + 5 * LDH + 3 * t; d[0] = __uint_as_float(u5v.x); d[1] = __uint_as_float(u5v.y); d[2] = __uint_as_float(u5v.z);
            d = ht + 6 * LDH + 3 * t; d[0] = __uint_as_float(u6v.x); d[1] = __uint_as_float(u6v.y); d[2] = __uint_as_float(u6v.z);
            d = ht + 7 * LDH + 3 * t; d[0] = __uint_as_float(u7v.x); d[1] = __uint_as_float(u7v.y); d[2] = __uint_as_float(u7v.z);
        }
        __syncthreads();

        // ---- compute half B (b = 8..15) ----
        {
            float a[3][8];
            #pragma unroll
            for (int j = 0; j < 3; j++)
                #pragma unroll
                for (int b = 0; b < 8; b++) a[j][b] = 0.f;
            if (s > 0) {
                #pragma unroll
                for (int sub = 0; sub < 3; sub++) {
                    const f4_t w00 = wp4[((0 * 3 + sub) * 2 + 0) * NT + t];
                    const f4_t w01 = wp4[((0 * 3 + sub) * 2 + 1) * NT + t];
                    const f4_t w10 = wp4[((1 * 3 + sub) * 2 + 0) * NT + t];
                    const f4_t w11 = wp4[((1 * 3 + sub) * 2 + 1) * NT + t];
                    const f4_t w20 = wp4[((2 * 3 + sub) * 2 + 0) * NT + t];
                    const f4_t w21 = wp4[((2 * 3 + sub) * 2 + 1) * NT + t];
                    const float* hb = ht + ks * 24 + sub * 8;
                    #pragma unroll
                    for (int b = 0; b < 8; b++) {
                        const f4_t h0v = *reinterpret_cast<const f4_t*>(hb + b * LDH);
                        const f4_t h1v = *reinterpret_cast<const f4_t*>(hb + b * LDH + 4);
                        float acc;
                        acc = a[0][b];
                        acc = fmaf(w00.x, h0v.x, acc); acc = fmaf(w00.y, h0v.y, acc);
                        acc = fmaf(w00.z, h0v.z, acc); acc = fmaf(w00.w, h0v.w, acc);
                        acc = fmaf(w01.x, h1v.x, acc); acc = fmaf(w01.y, h1v.y, acc);
                        acc = fmaf(w01.z, h1v.z, acc); acc = fmaf(w01.w, h1v.w, acc);
                        a[0][b] = acc;
                        acc = a[1][b];
                        acc = fmaf(w10.x, h0v.x, acc); acc = fmaf(w10.y, h0v.y, acc);
                        acc = fmaf(w10.z, h0v.z, acc); acc = fmaf(w10.w, h0v.w, acc);
                        acc = fmaf(w11.x, h1v.x, acc); acc = fmaf(w11.y, h1v.y, acc);
                        acc = fmaf(w11.z, h1v.z, acc); acc = fmaf(w11.w, h1v.w, acc);
                        a[1][b] = acc;
                        acc = a[2][b];
                        acc = fmaf(w20.x, h0v.x, acc); acc = fmaf(w20.y, h0v.y, acc);
                        acc = fmaf(w20.z, h0v.z, acc); acc = fmaf(w20.w, h0v.w, acc);
                        acc = fmaf(w21.x, h1v.x, acc); acc = fmaf(w21.y, h1v.y, acc);
                        acc = fmaf(w21.z, h1v.z, acc); acc = fmaf(w21.w, h1v.w, acc);
                        a[2][b] = acc;
                    }
                }
            }
            #pragma unroll
            for (int j = 0; j < 3; j++)
                #pragma unroll
                for (int b = 0; b < 8; b++) {
                    float v = a[j][b];
                    v += __shfl_xor(v, 8);
                    v += __shfl_xor(v, 16);
                    v += __shfl_xor(v, 32);
                    if (lane < 8)
                        pbuf[wv * PSS + (prow3 + j) * PRS + (b + 8)] = v;
                }
        }
        __syncthreads();   // pbuf complete

        // ---- final reduce + bias from xg ----
        {
            float dot = xgv;
            #pragma unroll
            for (int wq = 0; wq < 6; wq++)
                dot += pbuf[wq * PSS + r_row * PRS + r_b];
            gbuf[t] = dot;
        }
        __syncthreads();

        // ---- gates ----
        if (t < 96) {
            int l = t >> 4, b = t & 15;
            float gi = gbuf[(0 * CHUNK + l) * 16 + b];
            float gf = gbuf[(1 * CHUNK + l) * 16 + b];
            float gg = gbuf[(2 * CHUNK + l) * 16 + b];
            float go = gbuf[(3 * CHUNK + l) * 16 + b];
            float iv = 1.f / (1.f + expf(-gi));
            float fv = 1.f / (1.f + expf(-gf));
            float gv = tanhf(gg);
            float ov = 1.f / (1.f + expf(-go));
            float c  = fv * cbuf[t] + iv * gv;
            cbuf[t]  = c;
            float hv = ov * tanhf(c);
            hv = ((h0 + l) < H) ? hv : 0.f;
            hlx[b * CHUNK + l] = hv;
            if ((h0 + l) < H)
                xout[(size_t)b * ((size_t)SS * H) + (size_t)s * H + (h0 + l)] = hv;
        }
        __syncthreads();

        // ---- pack + publish this block's 2 chunks per batch row ----
        if (t < 32) {
            int bq = t >> 1, cj = t & 1;
            u4_t pk;
            pk.x = __float_as_uint(hlx[bq * CHUNK + 3 * cj + 0]);
            pk.y = __float_as_uint(hlx[bq * CHUNK + 3 * cj + 1]);
            pk.z = __float_as_uint(hlx[bq * CHUNK + 3 * cj + 2]);
            pk.w = tgt + 1u;
            llc_store_u4_drain(hpb + bq * NSTR + (h0 / 3 + cj), pk);
        }
    }
}

// ============================ persistent LSTM recurrence (r10, control + L2) ============================
template<int SW, int NCHR>
__global__ __launch_bounds__(NT, 1) void lstm_rec(
        const float* __restrict__ Whh,   // [4H][H]
        const float* __restrict__ xg,    // [S][B][4H]
        float* __restrict__ xout,        // [B][S][H]
        u4_t* __restrict__ hx,           // [2][16][NSTR] chunks
        int H, unsigned TB) {
    constexpr int KP   = 48 * SW;
    constexpr int LDH  = KP + 4;
    constexpr int NSUB = SW / 8;
    constexpr int PRS  = 17;
    constexpr int PSS  = 24 * PRS + 4;
    extern __shared__ __align__(16) float lds[];
    float* ht   = lds;
    float* pbuf = ht + 16 * LDH;
    float* gbuf = pbuf + 24 * PSS;
    float* cbuf = gbuf + NT;
    float* hlx  = cbuf + 96;

    const int t    = threadIdx.x;
    const int lane = t & 63;
    const int wv   = t >> 6;
    const int ks   = t >> 3;
    const int rg   = t & 7;
    const int h0   = blockIdx.x * CHUNK;
    const int G4   = 4 * H;

    const float* wr[3];
    #pragma unroll
    for (int j = 0; j < 3; j++) {
        int r = 3 * rg + j, g = r / CHUNK, l = r - g * CHUNK;
        int grow = ((h0 + l) < H) ? (g * H + h0 + l) : 0;
        wr[j] = Whh + (size_t)grow * (size_t)H;
    }

    for (int i = t; i < 16 * LDH; i += NT) ht[i] = 0.f;
    if (t < 96) cbuf[t] = 0.f;
    __syncthreads();

    const int r_row = t >> 4, r_b = t & 15;
    const int r_g = r_row / CHUNK, r_l = r_row - r_g * CHUNK;
    const int r_h = ((h0 + r_l) < H) ? (h0 + r_l) : h0;
    const float* xgp = xg + (size_t)r_b * G4 + (size_t)r_g * H + r_h;

    const int pairidx = (lane >> 4) & 3;
    const int prow3   = 3 * (lane & 7);

    #pragma unroll 1
    for (int s = 0; s < SS; s++) {
        const u4_t* hcb = hx + (size_t)(s & 1) * (16 * NSTR);
        u4_t*       hpb = hx + (size_t)((s + 1) & 1) * (16 * NSTR);
        const unsigned tgt = TB + (unsigned)s;
        float xgv = xgp[(size_t)s * (size_t)(16 * G4)];

        if (s > 0 && t < NCHR) {
            const u4_t* cb = hcb + t;
            #pragma unroll
            for (int rh = 0; rh < 2; rh++) {
                const u4_t* q0 = cb + (rh * 8 + 0) * NSTR;
                const u4_t* q1 = cb + (rh * 8 + 1) * NSTR;
                const u4_t* q2 = cb + (rh * 8 + 2) * NSTR;
                const u4_t* q3 = cb + (rh * 8 + 3) * NSTR;
                const u4_t* q4 = cb + (rh * 8 + 4) * NSTR;
                const u4_t* q5 = cb + (rh * 8 + 5) * NSTR;
                const u4_t* q6 = cb + (rh * 8 + 6) * NSTR;
                const u4_t* q7 = cb + (rh * 8 + 7) * NSTR;
                u4_t u0, u1, u2, u3, u4v, u5v, u6v, u7v;
                for (;;) {
                    llc_load8_wait(u0, u1, u2, u3, u4v, u5v, u6v, u7v,
                                   q0, q1, q2, q3, q4, q5, q6, q7);
                    int ok = (u0.w >= tgt) & (u1.w >= tgt) & (u2.w >= tgt) & (u3.w >= tgt)
                           & (u4v.w >= tgt) & (u5v.w >= tgt) & (u6v.w >= tgt) & (u7v.w >= tgt);
                    if (ok) break;
                }
                float* d;
                d = ht + (rh * 8 + 0) * LDH + 3 * t;
                d[0] = __uint_as_float(u0.x); d[1] = __uint_as_float(u0.y); d[2] = __uint_as_float(u0.z);
                d = ht + (rh * 8 + 1) * LDH + 3 * t;
                d[0] = __uint_as_float(u1.x); d[1] = __uint_as_float(u1.y); d[2] = __uint_as_float(u1.z);
                d = ht + (rh * 8 + 2) * LDH + 3 * t;
                d[0] = __uint_as_float(u2.x); d[1] = __uint_as_float(u2.y); d[2] = __uint_as_float(u2.z);
                d = ht + (rh * 8 + 3) * LDH + 3 * t;
                d[0] = __uint_as_float(u3.x); d[1] = __uint_as_float(u3.y); d[2] = __uint_as_float(u3.z);
                d = ht + (rh * 8 + 4) * LDH + 3 * t;
                d[0] = __uint_as_float(u4v.x); d[1] = __uint_as_float(u4v.y); d[2] = __uint_as_float(u4v.z);
                d = ht + (rh * 8 + 5) * LDH + 3 * t;
                d[0] = __uint_as_float(u5v.x); d[1] = __uint_as_float(u5v.y); d[2] = __uint_as_float(u5v.z);
                d = ht + (rh * 8 + 6) * LDH + 3 * t;
                d[0] = __uint_as_float(u6v.x); d[1] = __uint_as_float(u6v.y); d[2] = __uint_as_float(u6v.z);
                d = ht + (rh * 8 + 7) * LDH + 3 * t;
                d[0] = __uint_as_float(u7v.x); d[1] = __uint_as_float(u7v.y); d[2] = __uint_as_float(u7v.z);
            }
        }
        __syncthreads();

        float a[3][16];
        #pragma unroll
        for (int j = 0; j < 3; j++)
            #pragma unroll
            for (int b = 0; b < 16; b++) a[j][b] = 0.f;

        if (s > 0) {
            #pragma unroll
            for (int sub = 0; sub < NSUB; sub++) {
                const int kk = ks * SW + sub * 8;
                const int k0 = (kk < H) ? kk : 0;
                const int k1 = (kk + 4 < H) ? (kk + 4) : 0;
                const f4_t w00 = load_f4u(wr[0] + k0), w01 = load_f4u(wr[0] + k1);
                const f4_t w10 = load_f4u(wr[1] + k0), w11 = load_f4u(wr[1] + k1);
                const f4_t w20 = load_f4u(wr[2] + k0), w21 = load_f4u(wr[2] + k1);
                const float* hb = ht + kk;
                #pragma unroll
                for (int b = 0; b < 16; b++) {
                    const f4_t h0v = *reinterpret_cast<const f4_t*>(hb + b * LDH);
                    const f4_t h1v = *reinterpret_cast<const f4_t*>(hb + b * LDH + 4);
                    float acc;
                    acc = a[0][b];
                    acc = fmaf(w00.x, h0v.x, acc); acc = fmaf(w00.y, h0v.y, acc);
                    acc = fmaf(w00.z, h0v.z, acc); acc = fmaf(w00.w, h0v.w, acc);
                    acc = fmaf(w01.x, h1v.x, acc); acc = fmaf(w01.y, h1v.y, acc);
                    acc = fmaf(w01.z, h1v.z, acc); acc = fmaf(w01.w, h1v.w, acc);
                    a[0][b] = acc;
                    acc = a[1][b];
                    acc = fmaf(w10.x, h0v.x, acc); acc = fmaf(w10.y, h0v.y, acc);
                    acc = fmaf(w10.z, h0v.z, acc); acc = fmaf(w10.w, h0v.w, acc);
                    acc = fmaf(w11.x, h1v.x, acc); acc = fmaf(w11.y, h1v.y, acc);
                    acc = fmaf(w11.z, h1v.z, acc); acc = fmaf(w11.w, h1v.w, acc);
                    a[1][b] = acc;
                    acc = a[2][b];
                    acc = fmaf(w20.x, h0v.x, acc); acc = fmaf(w20.y, h0v.y, acc);
                    acc = fmaf(w20.z, h0v.z, acc); acc = fmaf(w20.w, h0v.w, acc);
                    acc = fmaf(w21.x, h1v.x, acc); acc = fmaf(w21.y, h1v.y, acc);
                    acc = fmaf(w21.z, h1v.z, acc); acc = fmaf(w21.w, h1v.w, acc);
                    a[2][b] = acc;
                }
            }
        }

        #pragma unroll
        for (int j = 0; j < 3; j++)
            #pragma unroll
            for (int b = 0; b < 16; b++) {
                float v = a[j][b] + __shfl_xor(a[j][b], 8);
                if ((lane & 8) == 0)
                    pbuf[(wv * 4 + pairidx) * PSS + (prow3 + j) * PRS + b] = v;
            }
        __syncthreads();

        {
            float dot = xgv;
            #pragma unroll
            for (int q = 0; q < 24; q++)
                dot += pbuf[q * PSS + r_row * PRS + r_b];
            gbuf[t] = dot;
        }
        __syncthreads();

        if (t < 96) {
            int l = t >> 4, b = t & 15;
            float gi = gbuf[(0 * CHUNK + l) * 16 + b];
            float gf = gbuf[(1 * CHUNK + l) * 16 + b];
            float gg = gbuf[(2 * CHUNK + l) * 16 + b];
            float go = gbuf[(3 * CHUNK + l) * 16 + b];
            float iv = 1.f / (1.f + expf(-gi));
            float fv = 1.f / (1.f + expf(-gf));
            float gv = tanhf(gg);
            float ov = 1.f / (1.f + expf(-go));
            float c  = fv * cbuf[t] + iv * gv;
            cbuf[t]  = c;
            float hv = ov * tanhf(c);
            hv = ((h0 + l) < H) ? hv : 0.f;
            hlx[b * CHUNK + l] = hv;
            if ((h0 + l) < H)
                xout[(size_t)b * ((size_t)SS * H) + (size_t)s * H + (h0 + l)] = hv;
        }
        __syncthreads();

        if (t < 32) {
            int bq = t >> 1, cj = t & 1;
            u4_t pk;
            pk.x = __float_as_uint(hlx[bq * CHUNK + 3 * cj + 0]);
            pk.y = __float_as_uint(hlx[bq * CHUNK + 3 * cj + 1]);
            pk.z = __float_as_uint(hlx[bq * CHUNK + 3 * cj + 2]);
            pk.w = tgt + 1u;
            llc_store_u4_drain(hpb + bq * NSTR + (h0 / 3 + cj), pk);
        }
    }
}

// ============================ launch ============================
extern "C" void kernel_launch(void* const* d_in, const int* in_sizes, int n_in,
                              void* d_out, int out_size, void* d_ws, size_t ws_size,
                              hipStream_t stream) {
    const int*   ids  = (const int*)d_in[0];
    const float* emb  = (const float*)d_in[1];
    const float* Wih0 = (const float*)d_in[2];
    const float* Whh0 = (const float*)d_in[3];
    const float* bih0 = (const float*)d_in[4];
    const float* bhh0 = (const float*)d_in[5];
    const float* Wih1 = (const float*)d_in[6];
    const float* Whh1 = (const float*)d_in[7];
    const float* bih1 = (const float*)d_in[8];
    const float* bhh1 = (const float*)d_in[9];
    const float* Wih2 = (const float*)d_in[10];
    const float* Whh2 = (const float*)d_in[11];
    const float* bih2 = (const float*)d_in[12];
    const float* bhh2 = (const float*)d_in[13];
    float* out = (float*)d_out;

    // workspace layout (floats)
    float* ws = (float*)d_ws;
    float* xA = ws;                        // 1,228,800  (x0, later x3)
    float* xB = xA + 1228800;              // 4,710,400  (x1, later x2; then final Ah/Al)
    float* xg = xB + 4710400;              // 18,841,600 (gates; then final Wh/Wl)
    u4_t*  hx = (u4_t*)(xg + 18841600);    // [2][16][NSTR] chunks = 196,608 B
    (void)in_sizes; (void)n_in; (void)out_size; (void)ws_size;

    // d_out as scratch for input-projection splits (fully rewritten at the end)
    ushort_t* sc  = (ushort_t*)d_out;
    ushort_t* tAh = sc;                               // [4096][1152] max
    ushort_t* tAl = tAh + (size_t)4096 * 1152;
    ushort_t* W0h = tAl + (size_t)4096 * 1152;        // [4608][320]
    ushort_t* W0l = W0h + (size_t)4608 * 320;
    ushort_t* W1h = W0l + (size_t)4608 * 320;         // [4608][1152]
    ushort_t* W1l = W1h + (size_t)4608 * 1152;
    ushort_t* W2h = W1l + (size_t)4608 * 1152;        // [1280][1152]
    ushort_t* W2l = W2h + (size_t)1280 * 1152;

    // final-projection splits (workspace regions dead by then)
    ushort_t* fAh = (ushort_t*)xB;                    // [4096][320]
    ushort_t* fAl = fAh + (size_t)4096 * 320;
    ushort_t* fWh = (ushort_t*)xg;                    // [32000][320]
    ushort_t* fWl = fWh + (size_t)32000 * 320;

    // zero tags once per launch (graph-captured, replay-safe)
    hipMemsetAsync(hx, 0, (size_t)2 * 16 * NSTR * 16, stream);

    // LDS bytes
    const size_t ldsW  = (size_t)(27648 + 9248 + 6 * 412 + NT + 96 + 96) * 4;    // 159,776 (treatment)
    const size_t lds01 = (size_t)(16 * 1156 + 24 * 412 + NT + 96 + 96) * 4;      // 115,840 (control)
    const size_t lds2  = (size_t)(16 * 388  + 24 * 412 + NT + 96 + 96) * 4;      //  66,688

    // ---- static weight splits ----
    conv_split<<<dim3(720), dim3(256), 0, stream>>>(Wih0, W0h, W0l, 4600, 300, 320, 4608 * 320);
    conv_split<<<dim3(2048), dim3(256), 0, stream>>>(Wih1, W1h, W1l, 4600, 1150, 1152, 4608 * 1152);
    conv_split<<<dim3(720), dim3(256), 0, stream>>>(Wih2, W2h, W2l, 1200, 1150, 1152, 1280 * 1152);

    // ---- embedding ----
    embed_kernel<<<dim3(BB * SS), dim3(256), 0, stream>>>(ids, emb, xA);

    // ---- layer 0 (TREATMENT: W-in-LDS recurrence) ----
    conv_split<<<dim3(640), dim3(256), 0, stream>>>(xA, tAh, tAl, 4096, 300, 320, 4096 * 320);
    gemm_mfma<<<dim3(36, 32), dim3(256), 0, stream>>>(tAh, tAl, W0h, W0l, xg,
                                                      4600, 320, bih0, bhh0, 1);
    lstm_recW<<<dim3(192), dim3(NT), ldsW, stream>>>(Whh0, xg, xB, hx, 1150, 0u);

    // ---- layer 1 (CONTROL: r10 W-streaming recurrence) ----
    conv_split<<<dim3(2048), dim3(256), 0, stream>>>(xB, tAh, tAl, 4096, 1150, 1152, 4096 * 1152);
    gemm_mfma<<<dim3(36, 32), dim3(256), 0, stream>>>(tAh, tAl, W1h, W1l, xg,
                                                      4600, 1152, bih1, bhh1, 1);
    lstm_rec<24, 384><<<dim3(192), dim3(NT), lds01, stream>>>(Whh1, xg, xB, hx, 1150, 256u);

    // ---- layer 2 ----
    conv_split<<<dim3(2048), dim3(256), 0, stream>>>(xB, tAh, tAl, 4096, 1150, 1152, 4096 * 1152);
    gemm_mfma<<<dim3(10, 32), dim3(256), 0, stream>>>(tAh, tAl, W2h, W2l, xg,
                                                      1200, 1152, bih2, bhh2, 1);
    lstm_rec<8, 100><<<dim3(50), dim3(NT), lds2, stream>>>(Whh2, xg, xA, hx, 300, 512u);

    // ---- final projection splits (xB/xg dead; d_out scratch no longer needed) ----
    conv_split<<<dim3(640), dim3(256), 0, stream>>>(xA, fAh, fAl, 4096, 300, 320, 4096 * 320);
    conv_split<<<dim3(2048), dim3(256), 0, stream>>>(emb, fWh, fWl, 32000, 300, 320, 32000 * 320);

    // ---- tied output projection via bf16-split MFMA ----
    gemm_mfma<<<dim3(250, 32), dim3(256), 0, stream>>>(fAh, fAl, fWh, fWl, out,
                                                       NVOCAB, 320, nullptr, nullptr, 0);
}